// Round 1
// baseline (631.346 us; speedup 1.0000x reference)
//
#include <hip/hip_runtime.h>
#include <math.h>

// Problem: B=2,H=16,S=1024,D=64 attention with additive biases + mask -> (-1e9),
// outputs BOTH context (B,H,S,D) and attn (B,H,S,S), all f32.
#define S_LEN 1024
#define D_DIM 64
#define NEGV  (-1.0e9f)
#define PSTR  1040          // padded P row stride in floats (1024+16) -> breaks bank aliasing

// One block = one (b*h, 16-q tile). 256 threads = 4 waves. 2048 blocks.
// LDS: Qst 4 KiB + Kt4 64 KiB + P 65 KiB = 133 KiB (< 160 KiB gfx950 cap), 1 block/CU.
__global__ __launch_bounds__(256, 1)
void attn_bias_fused(const float* __restrict__ Q, const float* __restrict__ K,
                     const float* __restrict__ V, const int* __restrict__ mif,
                     const float* __restrict__ iat, const float* __restrict__ iaf,
                     float* __restrict__ ctx, float* __restrict__ attn)
{
    __shared__ float  Qst[D_DIM][16];   // Q tile transposed: [d][q]
    __shared__ float4 Kt4[D_DIM][64];   // K chunk transposed, XOR-swizzled float4 cols
    __shared__ float  P[16][PSTR];      // score rows (f32), padded stride

    const int tid  = threadIdx.x;
    const int wave = tid >> 6;          // 0..3
    const int lane = tid & 63;
    const int bh   = blockIdx.x >> 6;   // 0..31
    const int qb   = (blockIdx.x & 63) << 4;

    const float* Qb = Q + ((size_t)(bh * S_LEN + qb)) * D_DIM;
    const float* Kb = K + ((size_t)bh * S_LEN) * D_DIM;
    const float* Vb = V + ((size_t)bh * S_LEN) * D_DIM;

    // ---- stage Q tile transposed (one-time; conflicts negligible) ----
    {
        int q = tid >> 4;            // 0..15
        int l = tid & 15;            // d4 index
        float4 v = *(const float4*)(Qb + (size_t)q * D_DIM + l * 4);
        Qst[4 * l + 0][q] = v.x;
        Qst[4 * l + 1][q] = v.y;
        Qst[4 * l + 2][q] = v.z;
        Qst[4 * l + 3][q] = v.w;
    }

    const int kg = lane;   // k column group (4 k's) within 256-chunk
    const int qg = wave;   // 4 q rows per wave

    // =================== QK^T + bias + mask -> P ===================
    for (int c = 0; c < 4; ++c) {
        __syncthreads();   // Kt4 reuse fence (also covers Qst staging on c==0)
        // stage K chunk (256 rows) transposed + swizzled. Global: 4x256B/instr coalesced.
        // LDS writes: bank = ((cc&7)*4 + (kk&3)) -> 2-way, free.
        {
            int l   = tid & 15;      // d4 index
            int kr0 = tid >> 4;      // 0..15
            #pragma unroll
            for (int i = 0; i < 16; ++i) {
                int kk = i * 16 + kr0;
                float4 v = *(const float4*)(Kb + (size_t)(c * 256 + kk) * D_DIM + l * 4);
                int cc  = (kk >> 2) ^ (l & 7);
                int sub = kk & 3;
                ((float*)&Kt4[4 * l + 0][cc])[sub] = v.x;
                ((float*)&Kt4[4 * l + 1][cc])[sub] = v.y;
                ((float*)&Kt4[4 * l + 2][cc])[sub] = v.z;
                ((float*)&Kt4[4 * l + 3][cc])[sub] = v.w;
            }
        }
        __syncthreads();

        // prefetch bias/mask for this chunk (independent loads; hide under FMA loop)
        float4 bt[4], bf[4];
        int4   bm[4];
        #pragma unroll
        for (int i = 0; i < 4; ++i) {
            size_t off = ((size_t)(bh * S_LEN + qb + qg * 4 + i)) * S_LEN + c * 256 + kg * 4;
            bt[i] = *(const float4*)(iat + off);
            bf[i] = *(const float4*)(iaf + off);
            bm[i] = *(const int4*)(mif + off);
        }

        // 4q x 4k dot over d=64. Kt4 read: b128 over a permuted contiguous 1KiB -> conflict-free.
        // Qst read: wave-uniform address -> broadcast, free.
        float4 a0 = {0.f, 0.f, 0.f, 0.f}, a1 = a0, a2 = a0, a3 = a0;
        #pragma unroll 16
        for (int d = 0; d < D_DIM; ++d) {
            float4 kv = Kt4[d][kg ^ ((d >> 2) & 7)];
            float4 qv = *(const float4*)&Qst[d][qg * 4];
            a0.x = fmaf(qv.x, kv.x, a0.x); a0.y = fmaf(qv.x, kv.y, a0.y);
            a0.z = fmaf(qv.x, kv.z, a0.z); a0.w = fmaf(qv.x, kv.w, a0.w);
            a1.x = fmaf(qv.y, kv.x, a1.x); a1.y = fmaf(qv.y, kv.y, a1.y);
            a1.z = fmaf(qv.y, kv.z, a1.z); a1.w = fmaf(qv.y, kv.w, a1.w);
            a2.x = fmaf(qv.z, kv.x, a2.x); a2.y = fmaf(qv.z, kv.y, a2.y);
            a2.z = fmaf(qv.z, kv.z, a2.z); a2.w = fmaf(qv.z, kv.w, a2.w);
            a3.x = fmaf(qv.w, kv.x, a3.x); a3.y = fmaf(qv.w, kv.y, a3.y);
            a3.z = fmaf(qv.w, kv.z, a3.z); a3.w = fmaf(qv.w, kv.w, a3.w);
        }

        // epilogue: scale 1/sqrt(64), +biases, mask -> -1e9, store row segment to P
        float4 av[4] = {a0, a1, a2, a3};
        #pragma unroll
        for (int i = 0; i < 4; ++i) {
            float4 s = av[i];
            float4 t = bt[i], f = bf[i];
            int4   m = bm[i];
            s.x = m.x ? NEGV : fmaf(s.x, 0.125f, t.x + f.x);
            s.y = m.y ? NEGV : fmaf(s.y, 0.125f, t.y + f.y);
            s.z = m.z ? NEGV : fmaf(s.z, 0.125f, t.z + f.z);
            s.w = m.w ? NEGV : fmaf(s.w, 0.125f, t.w + f.w);
            *(float4*)&P[qg * 4 + i][c * 256 + kg * 4] = s;
        }
    }
    __syncthreads();

    // =================== softmax over each row (k=0..1023) ===================
    // Row r handled by 16 lanes of one wave; interleaved k = 4*ks + 64*j keeps
    // LDS at 4-way worst case with PSTR=1040. Global attn write coalesced 4x256B.
    {
        int r  = wave * 4 + (lane >> 4);
        int ks = lane & 15;
        float* Prow = P[r];
        float mx = -INFINITY;
        #pragma unroll
        for (int j = 0; j < 16; ++j) {
            float4 v = *(const float4*)&Prow[(ks + 16 * j) * 4];
            mx = fmaxf(mx, fmaxf(fmaxf(v.x, v.y), fmaxf(v.z, v.w)));
        }
        #pragma unroll
        for (int s = 1; s < 16; s <<= 1) mx = fmaxf(mx, __shfl_xor(mx, s, 64));

        float sum = 0.f;
        #pragma unroll
        for (int j = 0; j < 16; ++j) {
            float4 v = *(const float4*)&Prow[(ks + 16 * j) * 4];
            v.x = __expf(v.x - mx);   // fully-masked row: -1e9-(-1e9)=0 -> exp=1 -> uniform, matches ref
            v.y = __expf(v.y - mx);
            v.z = __expf(v.z - mx);
            v.w = __expf(v.w - mx);
            sum += v.x + v.y + v.z + v.w;
            *(float4*)&Prow[(ks + 16 * j) * 4] = v;
        }
        #pragma unroll
        for (int s = 1; s < 16; s <<= 1) sum += __shfl_xor(sum, s, 64);
        float rinv = 1.f / sum;

        float* arow = attn + ((size_t)(bh * S_LEN + qb + r)) * S_LEN;
        #pragma unroll
        for (int j = 0; j < 16; ++j) {
            float4 v = *(const float4*)&Prow[(ks + 16 * j) * 4];
            v.x *= rinv; v.y *= rinv; v.z *= rinv; v.w *= rinv;
            *(float4*)&Prow[(ks + 16 * j) * 4] = v;
            *(float4*)(arow + (ks + 16 * j) * 4) = v;
        }
    }
    __syncthreads();   // P normalized for all rows before PV

    // =================== context = P @ V ===================
    // Wave w covers k in [w*256,(w+1)*256); lane: dg = d-quad, ks = k sub-slice.
    // P reads: 16-lane broadcast at 4 distinct bank quads -> free. V: global, coalesced, L2-hot.
    {
        int dg = lane & 15;
        int ks = lane >> 4;
        float4 accv[16];
        #pragma unroll
        for (int q = 0; q < 16; ++q) accv[q] = make_float4(0.f, 0.f, 0.f, 0.f);

        #pragma unroll 2
        for (int i = 0; i < 16; ++i) {
            int k0 = wave * 256 + i * 16 + ks * 4;
            const float* vrow = Vb + (size_t)k0 * D_DIM + dg * 4;
            float4 v0 = *(const float4*)(vrow + 0 * D_DIM);
            float4 v1 = *(const float4*)(vrow + 1 * D_DIM);
            float4 v2 = *(const float4*)(vrow + 2 * D_DIM);
            float4 v3 = *(const float4*)(vrow + 3 * D_DIM);
            #pragma unroll
            for (int q = 0; q < 16; ++q) {
                float4 p = *(const float4*)&P[q][k0];
                float4 a = accv[q];
                a.x = fmaf(p.x, v0.x, a.x); a.x = fmaf(p.y, v1.x, a.x);
                a.x = fmaf(p.z, v2.x, a.x); a.x = fmaf(p.w, v3.x, a.x);
                a.y = fmaf(p.x, v0.y, a.y); a.y = fmaf(p.y, v1.y, a.y);
                a.y = fmaf(p.z, v2.y, a.y); a.y = fmaf(p.w, v3.y, a.y);
                a.z = fmaf(p.x, v0.z, a.z); a.z = fmaf(p.y, v1.z, a.z);
                a.z = fmaf(p.z, v2.z, a.z); a.z = fmaf(p.w, v3.z, a.z);
                a.w = fmaf(p.x, v0.w, a.w); a.w = fmaf(p.y, v1.w, a.w);
                a.w = fmaf(p.z, v2.w, a.w); a.w = fmaf(p.w, v3.w, a.w);
                accv[q] = a;
            }
        }

        // cross-slice reduction through the (dead) Kt4 region: 16 slices x 1024 floats
        float* part = (float*)Kt4;
        int base = (wave * 4 + ks) * 1024 + dg * 4;
        #pragma unroll
        for (int q = 0; q < 16; ++q)
            *(float4*)(part + base + q * 64) = accv[q];
        __syncthreads();

        int q  = tid >> 4;
        int dr = tid & 15;
        float4 r = make_float4(0.f, 0.f, 0.f, 0.f);
        #pragma unroll
        for (int s = 0; s < 16; ++s) {
            float4 v = *(const float4*)(part + s * 1024 + q * 64 + dr * 4);
            r.x += v.x; r.y += v.y; r.z += v.z; r.w += v.w;
        }
        *(float4*)(ctx + ((size_t)(bh * S_LEN + qb + q)) * D_DIM + dr * 4) = r;
    }
}

extern "C" void kernel_launch(void* const* d_in, const int* in_sizes, int n_in,
                              void* d_out, int out_size, void* d_ws, size_t ws_size,
                              hipStream_t stream) {
    const float* Q   = (const float*)d_in[0];
    const float* K   = (const float*)d_in[1];
    const float* V   = (const float*)d_in[2];
    // d_in[3] = attn_mask (unused by reference), d_in[7] = distance_matrix (unused)
    const int*   mif = (const int*)d_in[4];    // attn_mask_if (bool -> int32)
    const float* iat = (const float*)d_in[5];
    const float* iaf = (const float*)d_in[6];

    float* ctx  = (float*)d_out;                       // (2,16,1024,64)
    float* attn = (float*)d_out + (size_t)2 * 16 * 1024 * 64;  // (2,16,1024,1024)

    dim3 grid(2048), block(256);
    hipLaunchKernelGGL(attn_bias_fused, grid, block, 0, stream,
                       Q, K, V, mif, iat, iaf, ctx, attn);
}

// Round 2
// 538.916 us; speedup vs baseline: 1.1715x; 1.1715x over previous
//
#include <hip/hip_runtime.h>
#include <math.h>

// B=2,H=16,S=1024,D=64 attention with additive biases + mask -> -1e9.
// Outputs context (B,H,S,D) and attn (B,H,S,S), f32.
//
// R2 design: scores live in REGISTERS (16 float4/lane = 4q x 16k), softmax via
// 64-lane shuffle reduction (no P LDS array -> kills the 9.7M bank conflicts),
// normalized P dumped into the dead K-tile LDS for the PV pass. LDS 72 KB ->
// 2 blocks/CU (8 waves/CU, was 4).
#define S_LEN 1024
#define D_DIM 64
#define NEGV  (-1.0e9f)

__global__ __launch_bounds__(256, 2)
void attn_bias_fused(const float* __restrict__ Q, const float* __restrict__ K,
                     const float* __restrict__ V, const int* __restrict__ mif,
                     const float* __restrict__ iat, const float* __restrict__ iaf,
                     float* __restrict__ ctx, float* __restrict__ attn)
{
    // 64 KB: K chunk (transposed+swizzled) during QK; reused as Pn[16][1024] for PV.
    __shared__ float4 Kt4[D_DIM][64];
    // 8 KB: Qst[64][16] (4 KB) during QK; scratch[4][8][64] during PV reduction.
    __shared__ float  SB[2048];

    float* Pn = (float*)Kt4;              // [16][1024], row stride 1024
    float (*Qst)[16] = (float(*)[16])SB;

    const int tid  = threadIdx.x;
    const int wave = tid >> 6;            // 0..3
    const int lane = tid & 63;
    const int bh   = blockIdx.x >> 6;     // 0..31
    const int qb   = (blockIdx.x & 63) << 4;

    const float* Qb = Q + ((size_t)(bh * S_LEN + qb)) * D_DIM;
    const float* Kb = K + ((size_t)bh * S_LEN) * D_DIM;
    const float* Vb = V + ((size_t)bh * S_LEN) * D_DIM;

    // ---- stage Q tile transposed ----
    {
        int q = tid >> 4, l = tid & 15;
        float4 v = *(const float4*)(Qb + (size_t)q * D_DIM + l * 4);
        Qst[4 * l + 0][q] = v.x;
        Qst[4 * l + 1][q] = v.y;
        Qst[4 * l + 2][q] = v.z;
        Qst[4 * l + 3][q] = v.w;
    }

    const int kg = lane;   // k quad within 256-chunk
    const int qg = wave;   // 4 q rows per wave

    float4 sc[16];         // sc[c*4+i]: row qg*4+i, k = c*256 + kg*4 .. +3

    // =================== QK^T + bias + mask -> registers ===================
    #pragma unroll
    for (int c = 0; c < 4; ++c) {
        __syncthreads();   // Kt4 reuse fence
        {
            int l = tid & 15, kr0 = tid >> 4;
            #pragma unroll
            for (int i = 0; i < 16; ++i) {
                int kk = i * 16 + kr0;
                float4 v = *(const float4*)(Kb + (size_t)(c * 256 + kk) * D_DIM + l * 4);
                int cc  = (kk >> 2) ^ (l & 7);
                int sub = kk & 3;
                ((float*)&Kt4[4 * l + 0][cc])[sub] = v.x;
                ((float*)&Kt4[4 * l + 1][cc])[sub] = v.y;
                ((float*)&Kt4[4 * l + 2][cc])[sub] = v.z;
                ((float*)&Kt4[4 * l + 3][cc])[sub] = v.w;
            }
        }
        __syncthreads();

        // prefetch bias/mask (independent; hides under the FMA loop)
        float4 bt[4], bf[4];
        int4   bm[4];
        #pragma unroll
        for (int i = 0; i < 4; ++i) {
            size_t off = ((size_t)(bh * S_LEN + qb + qg * 4 + i)) * S_LEN + c * 256 + kg * 4;
            bt[i] = *(const float4*)(iat + off);
            bf[i] = *(const float4*)(iaf + off);
            bm[i] = *(const int4*)(mif + off);
        }

        float4 a0 = {0.f, 0.f, 0.f, 0.f}, a1 = a0, a2 = a0, a3 = a0;
        #pragma unroll 16
        for (int d = 0; d < D_DIM; ++d) {
            float4 kv = Kt4[d][kg ^ ((d >> 2) & 7)];          // conflict-free b128
            float4 qv = *(const float4*)&Qst[d][qg * 4];       // wave-uniform broadcast
            a0.x = fmaf(qv.x, kv.x, a0.x); a0.y = fmaf(qv.x, kv.y, a0.y);
            a0.z = fmaf(qv.x, kv.z, a0.z); a0.w = fmaf(qv.x, kv.w, a0.w);
            a1.x = fmaf(qv.y, kv.x, a1.x); a1.y = fmaf(qv.y, kv.y, a1.y);
            a1.z = fmaf(qv.y, kv.z, a1.z); a1.w = fmaf(qv.y, kv.w, a1.w);
            a2.x = fmaf(qv.z, kv.x, a2.x); a2.y = fmaf(qv.z, kv.y, a2.y);
            a2.z = fmaf(qv.z, kv.z, a2.z); a2.w = fmaf(qv.z, kv.w, a2.w);
            a3.x = fmaf(qv.w, kv.x, a3.x); a3.y = fmaf(qv.w, kv.y, a3.y);
            a3.z = fmaf(qv.w, kv.z, a3.z); a3.w = fmaf(qv.w, kv.w, a3.w);
        }

        float4 av[4] = {a0, a1, a2, a3};
        #pragma unroll
        for (int i = 0; i < 4; ++i) {
            float4 s = av[i];
            float4 t = bt[i], f = bf[i];
            int4   m = bm[i];
            s.x = m.x ? NEGV : fmaf(s.x, 0.125f, t.x + f.x);
            s.y = m.y ? NEGV : fmaf(s.y, 0.125f, t.y + f.y);
            s.z = m.z ? NEGV : fmaf(s.z, 0.125f, t.z + f.z);
            s.w = m.w ? NEGV : fmaf(s.w, 0.125f, t.w + f.w);
            sc[c * 4 + i] = s;
        }
    }
    __syncthreads();   // all Kt4 reads done -> safe to reuse as Pn

    // =================== softmax in registers (64-lane shuffles) ===================
    {
        float mx[4], sum[4], rinv[4];
        #pragma unroll
        for (int i = 0; i < 4; ++i) {
            float m = -INFINITY;
            #pragma unroll
            for (int c = 0; c < 4; ++c) {
                float4 v = sc[c * 4 + i];
                m = fmaxf(m, fmaxf(fmaxf(v.x, v.y), fmaxf(v.z, v.w)));
            }
            #pragma unroll
            for (int s = 1; s < 64; s <<= 1) m = fmaxf(m, __shfl_xor(m, s, 64));
            mx[i] = m;
        }
        #pragma unroll
        for (int i = 0; i < 4; ++i) {
            float sm = 0.f;
            #pragma unroll
            for (int c = 0; c < 4; ++c) {
                float4 v = sc[c * 4 + i];
                v.x = __expf(v.x - mx[i]);   // all-masked row -> exp(0)=1 -> uniform, matches ref
                v.y = __expf(v.y - mx[i]);
                v.z = __expf(v.z - mx[i]);
                v.w = __expf(v.w - mx[i]);
                sc[c * 4 + i] = v;
                sm += v.x + v.y + v.z + v.w;
            }
            #pragma unroll
            for (int s = 1; s < 64; s <<= 1) sm += __shfl_xor(sm, s, 64);
            sum[i] = sm;
            rinv[i] = 1.f / sm;
        }
        // normalize; write attn (coalesced 1 KiB/row) + Pn (LDS, 2-way free)
        #pragma unroll
        for (int i = 0; i < 4; ++i) {
            int r = qg * 4 + i;
            float* arow = attn + ((size_t)(bh * S_LEN + qb + r)) * S_LEN;
            #pragma unroll
            for (int c = 0; c < 4; ++c) {
                float4 v = sc[c * 4 + i];
                v.x *= rinv[i]; v.y *= rinv[i]; v.z *= rinv[i]; v.w *= rinv[i];
                *(float4*)(arow + c * 256 + kg * 4)  = v;
                *(float4*)&Pn[r * 1024 + c * 256 + kg * 4] = v;
            }
        }
        (void)sum;
    }
    __syncthreads();   // Pn complete for all rows

    // =================== context = P @ V ===================
    // Wave w covers k in [w*256,(w+1)*256) for ALL 16 q rows (V read once/block).
    // lane: dg = d-quad, ks = k-sub; ks-groups reduced by shuffle afterwards.
    {
        int dg = lane & 15;
        int ks = lane >> 4;
        float4 acc[16];
        #pragma unroll
        for (int q = 0; q < 16; ++q) acc[q] = make_float4(0.f, 0.f, 0.f, 0.f);

        #pragma unroll 2
        for (int i = 0; i < 16; ++i) {
            int k0 = wave * 256 + i * 16 + ks * 4;
            const float* vrow = Vb + (size_t)k0 * D_DIM + dg * 4;
            float4 v0 = *(const float4*)(vrow + 0 * D_DIM);
            float4 v1 = *(const float4*)(vrow + 1 * D_DIM);
            float4 v2 = *(const float4*)(vrow + 2 * D_DIM);
            float4 v3 = *(const float4*)(vrow + 3 * D_DIM);
            #pragma unroll
            for (int q = 0; q < 16; ++q) {
                float4 p = *(const float4*)&Pn[q * 1024 + k0];   // 4-addr broadcast, free
                float4 a = acc[q];
                a.x = fmaf(p.x, v0.x, a.x); a.x = fmaf(p.y, v1.x, a.x);
                a.x = fmaf(p.z, v2.x, a.x); a.x = fmaf(p.w, v3.x, a.x);
                a.y = fmaf(p.x, v0.y, a.y); a.y = fmaf(p.y, v1.y, a.y);
                a.y = fmaf(p.z, v2.y, a.y); a.y = fmaf(p.w, v3.y, a.y);
                a.z = fmaf(p.x, v0.z, a.z); a.z = fmaf(p.y, v1.z, a.z);
                a.z = fmaf(p.z, v2.z, a.z); a.z = fmaf(p.w, v3.z, a.z);
                a.w = fmaf(p.x, v0.w, a.w); a.w = fmaf(p.y, v1.w, a.w);
                a.w = fmaf(p.z, v2.w, a.w); a.w = fmaf(p.w, v3.w, a.w);
                acc[q] = a;
            }
        }

        // reduce the 4 ks-groups within the wave (xor 16, 32); lanes 0..15 end complete
        #pragma unroll
        for (int q = 0; q < 16; ++q) {
            acc[q].x += __shfl_xor(acc[q].x, 16, 64);
            acc[q].y += __shfl_xor(acc[q].y, 16, 64);
            acc[q].z += __shfl_xor(acc[q].z, 16, 64);
            acc[q].w += __shfl_xor(acc[q].w, 16, 64);
            acc[q].x += __shfl_xor(acc[q].x, 32, 64);
            acc[q].y += __shfl_xor(acc[q].y, 32, 64);
            acc[q].z += __shfl_xor(acc[q].z, 32, 64);
            acc[q].w += __shfl_xor(acc[q].w, 32, 64);
        }

        // cross-wave reduction through 8 KB scratch (aliases dead Qst), 2 passes of 8 rows
        float* scratch = SB;   // [4 waves][8 q][64 d]
        #pragma unroll
        for (int qh = 0; qh < 2; ++qh) {
            __syncthreads();   // scratch free (Qst dead / previous pass read done)
            if (lane < 16) {
                #pragma unroll
                for (int j = 0; j < 8; ++j)
                    *(float4*)&scratch[(wave * 8 + j) * 64 + dg * 4] = acc[qh * 8 + j];
            }
            __syncthreads();
            if (tid < 128) {
                int qq = tid >> 4;           // 0..7
                int dr = tid & 15;
                float4 r = make_float4(0.f, 0.f, 0.f, 0.f);
                #pragma unroll
                for (int s = 0; s < 4; ++s) {
                    float4 v = *(const float4*)&scratch[(s * 8 + qq) * 64 + dr * 4];
                    r.x += v.x; r.y += v.y; r.z += v.z; r.w += v.w;
                }
                *(float4*)(ctx + ((size_t)(bh * S_LEN + qb + qh * 8 + qq)) * D_DIM + dr * 4) = r;
            }
        }
    }
}

extern "C" void kernel_launch(void* const* d_in, const int* in_sizes, int n_in,
                              void* d_out, int out_size, void* d_ws, size_t ws_size,
                              hipStream_t stream) {
    const float* Q   = (const float*)d_in[0];
    const float* K   = (const float*)d_in[1];
    const float* V   = (const float*)d_in[2];
    const int*   mif = (const int*)d_in[4];    // attn_mask_if
    const float* iat = (const float*)d_in[5];
    const float* iaf = (const float*)d_in[6];

    float* ctx  = (float*)d_out;
    float* attn = (float*)d_out + (size_t)2 * 16 * 1024 * 64;

    dim3 grid(2048), block(256);
    hipLaunchKernelGGL(attn_bias_fused, grid, block, 0, stream,
                       Q, K, V, mif, iat, iaf, ctx, attn);
}